// Round 3
// baseline (1104.233 us; speedup 1.0000x reference)
//
#include <hip/hip_runtime.h>

#define BB 4
#define CY 256
#define CM 128
#define HW 4096       // 64*64
#define HWy 1024      // 32*32
#define PHW 4356      // 66*66
#define EPSF 1e-5f
#define TWOPI 6.2831853071795864769f

struct c32 { float re, im; };

// ---------------- conv kernels ----------------

__global__ void conv1_kernel(const float* __restrict__ y, const float* __restrict__ w,
                             const float* __restrict__ g, const float* __restrict__ bb,
                             const float* __restrict__ m, const float* __restrict__ v,
                             float* __restrict__ y1){
  int p = blockIdx.x*256 + threadIdx.x;   // 0..1023
  int ocb = blockIdx.y*8;
  int b = blockIdx.z;
  float acc[8] = {0,0,0,0,0,0,0,0};
  const float* yb = y + (size_t)b*CY*HWy + p;
  #pragma unroll 4
  for(int ic=0; ic<CY; ic++){
    float xv = yb[(size_t)ic*HWy];
    #pragma unroll
    for(int j=0;j<8;j++) acc[j] += xv * w[(ocb+j)*CY + ic];
  }
  #pragma unroll
  for(int j=0;j<8;j++){
    int oc = ocb+j;
    float s = g[oc]*rsqrtf(v[oc]+EPSF);
    float bi = bb[oc] - m[oc]*s;
    float r = acc[j]*s + bi;
    y1[((size_t)(b*CM+oc))*HWy + p] = r>0.f?r:0.f;
  }
}

__global__ void qconv_kernel(const float* __restrict__ y1, const float* __restrict__ w,
                             float* __restrict__ q){
  int p = blockIdx.x*256 + threadIdx.x;  // 0..4095
  int ocb = blockIdx.y*8; int b = blockIdx.z;
  int mi = ((p>>7)<<5) + ((p&63)>>1);    // (h/2)*32 + w/2
  float acc[8] = {0,0,0,0,0,0,0,0};
  const float* yb = y1 + (size_t)b*CM*HWy + mi;
  #pragma unroll 4
  for(int ic=0; ic<CM; ic++){
    float xv = yb[(size_t)ic*HWy];
    #pragma unroll
    for(int j=0;j<8;j++) acc[j] += xv * w[(ocb+j)*CM+ic];
  }
  #pragma unroll
  for(int j=0;j<8;j++) q[((size_t)(b*CM+ocb+j))*HW + p] = acc[j];
}

__global__ void kvconv_kernel(const float* __restrict__ x, const float* __restrict__ kw,
                              const float* __restrict__ vw,
                              float* __restrict__ k, float* __restrict__ v){
  int p = blockIdx.x*256 + threadIdx.x;  // 0..4355 (guard)
  int ocb = blockIdx.y*8; int b = blockIdx.z;
  if(p >= PHW) return;
  int hh = p/66, ww2 = p - hh*66;
  int ih = hh-1, iw = ww2-1;
  bool inb = (ih>=0 && ih<64 && iw>=0 && iw<64);
  float acck[8] = {0,0,0,0,0,0,0,0};
  float accv[8] = {0,0,0,0,0,0,0,0};
  if(inb){
    const float* xb = x + (size_t)b*CM*HW + ih*64 + iw;
    #pragma unroll 4
    for(int ic=0; ic<CM; ic++){
      float xv = xb[(size_t)ic*HW];
      #pragma unroll
      for(int j=0;j<8;j++){ acck[j] += xv*kw[(ocb+j)*CM+ic]; accv[j] += xv*vw[(ocb+j)*CM+ic]; }
    }
  }
  #pragma unroll
  for(int j=0;j<8;j++){
    size_t o = ((size_t)(b*CM+ocb+j))*PHW + p;
    k[o]=acck[j]; v[o]=accv[j];
  }
}

// ---------------- attention ----------------

__global__ void attn_kernel(const float* __restrict__ q, const float* __restrict__ k,
                            const float* __restrict__ v, const float* __restrict__ relh,
                            const float* __restrict__ relw, float* __restrict__ xatt){
  int t = blockIdx.x*256 + threadIdx.x;  // over B*CM*HW
  int p = t & 4095;
  int bc = t >> 12;       // b*128+c
  int c = bc & 127;
  int h = p>>6, w2 = p&63;
  float qv = q[(size_t)bc*HW + p];
  const float* kb = k + (size_t)bc*PHW;
  const float* vb = v + (size_t)bc*PHW;
  float lg[9], vv[9];
  #pragma unroll
  for(int ti=0; ti<3; ti++){
    #pragma unroll
    for(int tj=0; tj<3; tj++){
      int idx = (h+ti)*66 + (w2+tj);
      float rel = (c<64) ? relh[c*3+ti] : relw[(c-64)*3+tj];
      float kv = kb[idx] + rel;
      lg[ti*3+tj] = qv*kv;
      vv[ti*3+tj] = vb[idx];
    }
  }
  float mx = lg[0];
  #pragma unroll
  for(int i=1;i<9;i++) mx = fmaxf(mx, lg[i]);
  float s=0.f, o=0.f;
  #pragma unroll
  for(int i=0;i<9;i++){ float e = __expf(lg[i]-mx); s += e; o += e*vv[i]; }
  xatt[t] = o/s;
}

// ---------------- FFT helpers ----------------

template<int SIGN>
__device__ inline void dft8(const c32* a, c32* X){
  constexpr float C8[8] = {1.f,0.70710678118654752f,0.f,-0.70710678118654752f,
                           -1.f,-0.70710678118654752f,0.f,0.70710678118654752f};
  constexpr float S8[8] = {0.f,0.70710678118654752f,1.f,0.70710678118654752f,
                           0.f,-0.70710678118654752f,-1.f,-0.70710678118654752f};
  #pragma unroll
  for(int kk=0;kk<8;kk++){
    float xr=0.f, xi=0.f;
    #pragma unroll
    for(int n=0;n<8;n++){
      const int j=(n*kk)&7;
      const float wr = C8[j];
      const float wi = SIGN*S8[j];   // e^{SIGN*2pi i j/8}
      xr += a[n].re*wr - a[n].im*wi;
      xi += a[n].re*wi + a[n].im*wr;
    }
    X[kk].re=xr; X[kk].im=xi;
  }
}

// 64-pt FFT along an axis; 32 lines/block x 8 threads; line l: base=(l/l_div)*s1+(l%l_div)*s2
template<int SIGN, bool RIN, bool ROUT>
__global__ void fft64_kernel(const float* in, float* out,
                             int l_div, int s1, int s2, int estride, float scale){
  __shared__ c32 tmp[32][65];
  int ll = threadIdx.x & 31;
  int j  = threadIdx.x >> 5;   // n2 in pass1, k1 in pass2
  int l = blockIdx.x*32 + ll;
  int base = (l/l_div)*s1 + (l%l_div)*s2;
  c32 a[8];
  #pragma unroll
  for(int n1=0;n1<8;n1++){
    int e = n1*8 + j;
    if(RIN){ a[n1].re = in[base + e*estride]; a[n1].im = 0.f; }
    else { const float2* ci = (const float2*)in; float2 t2 = ci[base + e*estride]; a[n1].re=t2.x; a[n1].im=t2.y; }
  }
  c32 A[8];
  dft8<SIGN>(a, A);
  #pragma unroll
  for(int k1=0;k1<8;k1++){
    float ang = SIGN * (TWOPI/64.f) * (float)(j*k1);
    float sn, cs; __sincosf(ang, &sn, &cs);
    c32 t; t.re = A[k1].re*cs - A[k1].im*sn; t.im = A[k1].re*sn + A[k1].im*cs;
    tmp[ll][k1*8+j] = t;
  }
  __syncthreads();
  c32 bv[8];
  #pragma unroll
  for(int n2=0;n2<8;n2++) bv[n2] = tmp[ll][j*8+n2];
  c32 Y[8];
  dft8<SIGN>(bv, Y);
  #pragma unroll
  for(int k2=0;k2<8;k2++){
    int e = j + 8*k2;
    int oi = base + e*estride;
    if(ROUT) out[oi] = Y[k2].re*scale;
    else { float2* co = (float2*)out; co[oi] = make_float2(Y[k2].re*scale, Y[k2].im*scale); }
  }
}

// 128-pt FFT along channel axis, in-place; 16 lines/block x 16 threads
template<int SIGN>
__global__ void fft128_kernel(float* data, float scale){
  __shared__ c32 tmp[16][129];
  int ll = threadIdx.x & 15;
  int j  = threadIdx.x >> 4;   // n2 = 0..15
  int l = blockIdx.x*16 + ll;  // 0..16383 : (b, hf*64+wf)
  int b = l >> 12;
  int rem = l & 4095;
  size_t base = (size_t)b*CM*HW + rem;
  float2* cd = (float2*)data;
  c32 a[8];
  #pragma unroll
  for(int n1=0;n1<8;n1++){
    float2 t2 = cd[base + (size_t)(16*n1 + j)*HW];
    a[n1].re=t2.x; a[n1].im=t2.y;
  }
  c32 A[8];
  dft8<SIGN>(a, A);
  #pragma unroll
  for(int k1=0;k1<8;k1++){
    float ang = SIGN*(TWOPI/128.f)*(float)(j*k1);
    float sn,cs; __sincosf(ang,&sn,&cs);
    c32 t; t.re = A[k1].re*cs - A[k1].im*sn; t.im = A[k1].re*sn + A[k1].im*cs;
    tmp[ll][k1*16 + j] = t;
  }
  __syncthreads();
  int k1 = j & 7, half = j >> 3;
  c32 bv[16];
  #pragma unroll
  for(int n2=0;n2<16;n2++) bv[n2] = tmp[ll][k1*16+n2];
  #pragma unroll
  for(int kk=0;kk<8;kk++){
    int k2 = half*8 + kk;
    float xr=0.f, xi=0.f;
    #pragma unroll
    for(int n2=0;n2<16;n2++){
      float ang = SIGN*(TWOPI/16.f)*(float)((n2*k2)&15);
      float sn,cs; __sincosf(ang,&sn,&cs);
      xr += bv[n2].re*cs - bv[n2].im*sn;
      xi += bv[n2].re*sn + bv[n2].im*cs;
    }
    cd[base + (size_t)(k1 + 8*k2)*HW] = make_float2(xr*scale, xi*scale);
  }
}

// ---------------- batch FFT4 pre-pass ----------------
// Xb[kb,i,f] = FFT4 over batch of Xf[b,i,f] (sign -1, unscaled; scale folded in fft128)
// One-shot hoist of the butterfly out of the einsum i-loop (it was recomputed 128x
// and 4x-redundantly across the block's waves). float4 = two consecutive f.
__global__ void fft4b_kernel(const float4* __restrict__ E4, float4* __restrict__ Eb4){
  int t = blockIdx.x*256 + threadIdx.x;  // 0 .. CM*2048-1 (i, f-pair)
  int i  = t >> 11;
  int fp = t & 2047;
  float4 x0 = E4[(size_t)(0*CM+i)*2048 + fp];
  float4 x1 = E4[(size_t)(1*CM+i)*2048 + fp];
  float4 x2 = E4[(size_t)(2*CM+i)*2048 + fp];
  float4 x3 = E4[(size_t)(3*CM+i)*2048 + fp];
  float4 y0, y1, y2, y3;
  // half 0 (.x=re,.y=im)
  y0.x = x0.x+x1.x+x2.x+x3.x;       y0.y = x0.y+x1.y+x2.y+x3.y;
  y1.x = x0.x + x1.y - x2.x - x3.y; y1.y = x0.y - x1.x - x2.y + x3.x;
  y2.x = x0.x - x1.x + x2.x - x3.x; y2.y = x0.y - x1.y + x2.y - x3.y;
  y3.x = x0.x - x1.y - x2.x + x3.y; y3.y = x0.y + x1.x - x2.y - x3.x;
  // half 1 (.z=re,.w=im)
  y0.z = x0.z+x1.z+x2.z+x3.z;       y0.w = x0.w+x1.w+x2.w+x3.w;
  y1.z = x0.z + x1.w - x2.z - x3.w; y1.w = x0.w - x1.z - x2.w + x3.z;
  y2.z = x0.z - x1.z + x2.z - x3.z; y2.w = x0.w - x1.w + x2.w - x3.w;
  y3.z = x0.z - x1.w - x2.z + x3.w; y3.w = x0.w + x1.z - x2.w - x3.z;
  Eb4[(size_t)(0*CM+i)*2048 + fp] = y0;
  Eb4[(size_t)(1*CM+i)*2048 + fp] = y1;
  Eb4[(size_t)(2*CM+i)*2048 + fp] = y2;
  Eb4[(size_t)(3*CM+i)*2048 + fp] = y3;
}

// ---------------- channel-mixing einsum (+mask) ----------------
// out_ft[kb,o,f] = sum_i Xb[kb,i,f]*w1[i,o,f]
// v3: f-pair per thread (wide loads: dwordx4 Xb, dwordx2 w), unroll-4 software
// pipeline (launch_bounds caps VGPR at 128 -> full 4-blocks/CU residency),
// bijective XCD swizzle keeps each f-chunk's Xb (512KB) resident in one XCD L2.
#define CMAC(A, B, W_r, W_i) \
  A.x += B.x*W_r.x - B.y*W_i.x; \
  A.y += B.x*W_i.x + B.y*W_r.x; \
  A.z += B.z*W_r.y - B.w*W_i.y; \
  A.w += B.z*W_i.y + B.w*W_r.y;

__global__ __launch_bounds__(256,4)
void einsum_kernel(const float4* __restrict__ Xb4, const float2* __restrict__ w1r2,
                   const float2* __restrict__ w1i2, float4* __restrict__ OutF4){
  // 1024 blocks; 1024 % 8 == 0 -> bijective remap; same f-chunk -> same XCD
  int L = blockIdx.x;
  int wk = (L & 7) * 128 + (L >> 3);
  int obase = (wk & 31) * 4;           // 32 o-groups of 4
  int fbase = (wk >> 5) * 128;         // 32 f-chunks of 128
  int fl = threadIdx.x & 63;
  int ol = threadIdx.x >> 6;           // 0..3
  int f0 = fbase + fl*2;               // this thread: f0, f0+1
  int o  = obase + ol;
  int fp = f0 >> 1;                    // float4 / float2 pair index
  float4 acc0 = make_float4(0.f,0.f,0.f,0.f);
  float4 acc1 = make_float4(0.f,0.f,0.f,0.f);
  float4 acc2 = make_float4(0.f,0.f,0.f,0.f);
  float4 acc3 = make_float4(0.f,0.f,0.f,0.f);
  const float4* X0 = Xb4 + fp;
  const float2* wr0 = w1r2 + (size_t)o*2048 + fp;
  const float2* wi0 = w1i2 + (size_t)o*2048 + fp;
  #pragma unroll 4
  for(int i=0;i<CM;i++){
    float4 b0 = X0[(size_t)(0*CM+i)*2048];
    float4 b1 = X0[(size_t)(1*CM+i)*2048];
    float4 b2 = X0[(size_t)(2*CM+i)*2048];
    float4 b3 = X0[(size_t)(3*CM+i)*2048];
    float2 wr = wr0[(size_t)i*CM*2048];
    float2 wi = wi0[(size_t)i*CM*2048];
    CMAC(acc0, b0, wr, wi)
    CMAC(acc1, b1, wr, wi)
    CMAC(acc2, b2, wr, wi)
    CMAC(acc3, b3, wr, wi)
  }
  int hf = f0>>6;
  int wf0 = f0&63, wf1 = wf0+1;
  bool mh = (hf<3 || hf>60);
  bool m0 = mh && (wf0<3 || wf0>60);
  bool m1 = mh && (wf1<3 || wf1>60);
  if(m0){ acc0.x=0.f;acc0.y=0.f; acc1.x=0.f;acc1.y=0.f; acc2.x=0.f;acc2.y=0.f; acc3.x=0.f;acc3.y=0.f; }
  if(m1){ acc0.z=0.f;acc0.w=0.f; acc1.z=0.f;acc1.w=0.f; acc2.z=0.f;acc2.w=0.f; acc3.z=0.f;acc3.w=0.f; }
  OutF4[((size_t)(0*CM + o))*2048 + fp] = acc0;
  OutF4[((size_t)(1*CM + o))*2048 + fp] = acc1;
  OutF4[((size_t)(2*CM + o))*2048 + fp] = acc2;
  OutF4[((size_t)(3*CM + o))*2048 + fp] = acc3;
}

// ---------------- final combine: w0 conv + blend + bn2 + relu ----------------
__global__ void final_kernel(const float* __restrict__ G, const float* __restrict__ xatt,
                             const float* __restrict__ w0, const float* __restrict__ w0b,
                             const float* __restrict__ r1p, const float* __restrict__ r2p,
                             const float* __restrict__ g2, const float* __restrict__ b2,
                             const float* __restrict__ m2, const float* __restrict__ v2,
                             float* __restrict__ yout){
  int p = blockIdx.x*256 + threadIdx.x;  // 0..4095
  int ocb = blockIdx.y*8; int b = blockIdx.z;
  float r1 = r1p[0], r2 = r2p[0];
  float acc[8] = {0,0,0,0,0,0,0,0};
  const float* xb = xatt + (size_t)b*CM*HW + p;
  #pragma unroll 4
  for(int ic=0; ic<CM; ic++){
    float xv = xb[(size_t)ic*HW];
    #pragma unroll
    for(int j=0;j<8;j++) acc[j] += xv * w0[(ocb+j)*CM + ic];
  }
  #pragma unroll
  for(int j=0;j<8;j++){
    int oc = ocb+j;
    float fam = r1 * G[((size_t)(b*CM+oc))*HW + p] + r2*(acc[j] + w0b[oc]);
    float s = g2[oc]*rsqrtf(v2[oc]+EPSF);
    float bi = b2[oc] - m2[oc]*s;
    float val = fam*s + bi;
    yout[((size_t)(b*CM+oc))*HW + p] = val>0.f?val:0.f;
  }
}

extern "C" void kernel_launch(void* const* d_in, const int* in_sizes, int n_in,
                              void* d_out, int out_size, void* d_ws, size_t ws_size,
                              hipStream_t stream){
  const float* x       = (const float*)d_in[0];
  const float* y       = (const float*)d_in[1];
  const float* conv1_w = (const float*)d_in[2];
  const float* bn1_g   = (const float*)d_in[3];
  const float* bn1_b   = (const float*)d_in[4];
  const float* bn1_m   = (const float*)d_in[5];
  const float* bn1_v   = (const float*)d_in[6];
  const float* q_w     = (const float*)d_in[7];
  const float* k_w     = (const float*)d_in[8];
  const float* v_w     = (const float*)d_in[9];
  const float* rel_h   = (const float*)d_in[10];
  const float* rel_w   = (const float*)d_in[11];
  const float* rate1   = (const float*)d_in[12];
  const float* rate2   = (const float*)d_in[13];
  const float* w1r     = (const float*)d_in[14];
  const float* w1i     = (const float*)d_in[15];
  const float* w0_w    = (const float*)d_in[16];
  const float* w0_b    = (const float*)d_in[17];
  const float* bn2_g   = (const float*)d_in[18];
  const float* bn2_b   = (const float*)d_in[19];
  const float* bn2_m   = (const float*)d_in[20];
  const float* bn2_v   = (const float*)d_in[21];
  (void)in_sizes; (void)n_in; (void)out_size; (void)ws_size;

  char* ws = (char*)d_ws;
  // phase-1 buffers (dead before complex buffers are written)
  float* Y1 = (float*)(ws + 0);                 // 2 MB
  float* Q  = (float*)(ws + 2097152);           // 8 MB
  float* K  = (float*)(ws + 10485760);          // 8.7 MB
  float* V  = (float*)(ws + 19406848);          // 8.7 MB (ends 28,327,936)
  // phase-2 buffers (peak ws = 32 MB)
  float2* E  = (float2*)(ws + 0);               // 16 MB  (Xf: 2D-FFT + chan-FFT result)
  float2* Eb = (float2*)(ws + 16777216);        // 16 MB  (batch-FFT4 of E); E dead after
  float2* F  = (float2*)(ws + 0);               // 16 MB  (out_ft, over dead E)
  float*  G  = (float*)(ws + 16777216);         // 8 MB   (real ifft result, over dead Eb)

  float* yout = (float*)d_out;
  float* xatt = (float*)d_out + 2097152;

  conv1_kernel<<<dim3(4,16,BB),256,0,stream>>>(y, conv1_w, bn1_g,bn1_b,bn1_m,bn1_v, Y1);
  qconv_kernel<<<dim3(16,16,BB),256,0,stream>>>(Y1, q_w, Q);
  kvconv_kernel<<<dim3(18,16,BB),256,0,stream>>>(x, k_w, v_w, K, V);
  attn_kernel<<<dim3(8192),256,0,stream>>>(Q, K, V, rel_h, rel_w, xatt);

  // forward 2D FFT over (h,w): real xatt -> E, then in-place along h
  fft64_kernel<-1,true,false><<<dim3(1024),256,0,stream>>>(xatt, (float*)E, 64,4096,64, 1, 0.125f);
  fft64_kernel<-1,false,false><<<dim3(1024),256,0,stream>>>((float*)E, (float*)E, 64,4096,1, 64, 0.125f);
  // forward FFT along channel (scale includes 1/sqrt(128) and batch 1/2)
  fft128_kernel<-1><<<dim3(1024),256,0,stream>>>((float*)E, 0.044194173824159216f);
  // batch FFT4 hoisted out of the einsum loop
  fft4b_kernel<<<dim3(1024),256,0,stream>>>((const float4*)E, (float4*)Eb);
  // channel-mix + mask
  einsum_kernel<<<dim3(1024),256,0,stream>>>((const float4*)Eb, (const float2*)w1r,
                                             (const float2*)w1i, (float4*)F);
  // inverse 2D FFT over (h,w): in-place along h, then along w -> real G
  fft64_kernel<1,false,false><<<dim3(1024),256,0,stream>>>((float*)F, (float*)F, 64,4096,1, 64, 0.125f);
  fft64_kernel<1,false,true><<<dim3(1024),256,0,stream>>>((float*)F, G, 64,4096,64, 1, 0.125f);

  final_kernel<<<dim3(16,16,BB),256,0,stream>>>(G, xatt, w0_w, w0_b, rate1, rate2,
                                                bn2_g,bn2_b,bn2_m,bn2_v, yout);
}

// Round 4
// 825.544 us; speedup vs baseline: 1.3376x; 1.3376x over previous
//
#include <hip/hip_runtime.h>

#define BB 4
#define CY 256
#define CM 128
#define HW 4096       // 64*64
#define HWy 1024      // 32*32
#define PHW 4356      // 66*66
#define EPSF 1e-5f
#define TWOPI 6.2831853071795864769f

struct c32 { float re, im; };

// ---------------- conv kernels ----------------

__global__ void conv1_kernel(const float* __restrict__ y, const float* __restrict__ w,
                             const float* __restrict__ g, const float* __restrict__ bb,
                             const float* __restrict__ m, const float* __restrict__ v,
                             float* __restrict__ y1){
  int p = blockIdx.x*256 + threadIdx.x;   // 0..1023
  int ocb = blockIdx.y*8;
  int b = blockIdx.z;
  float acc[8] = {0,0,0,0,0,0,0,0};
  const float* yb = y + (size_t)b*CY*HWy + p;
  #pragma unroll 4
  for(int ic=0; ic<CY; ic++){
    float xv = yb[(size_t)ic*HWy];
    #pragma unroll
    for(int j=0;j<8;j++) acc[j] += xv * w[(ocb+j)*CY + ic];
  }
  #pragma unroll
  for(int j=0;j<8;j++){
    int oc = ocb+j;
    float s = g[oc]*rsqrtf(v[oc]+EPSF);
    float bi = bb[oc] - m[oc]*s;
    float r = acc[j]*s + bi;
    y1[((size_t)(b*CM+oc))*HWy + p] = r>0.f?r:0.f;
  }
}

__global__ void qconv_kernel(const float* __restrict__ y1, const float* __restrict__ w,
                             float* __restrict__ q){
  int p = blockIdx.x*256 + threadIdx.x;  // 0..4095
  int ocb = blockIdx.y*8; int b = blockIdx.z;
  int mi = ((p>>7)<<5) + ((p&63)>>1);    // (h/2)*32 + w/2
  float acc[8] = {0,0,0,0,0,0,0,0};
  const float* yb = y1 + (size_t)b*CM*HWy + mi;
  #pragma unroll 4
  for(int ic=0; ic<CM; ic++){
    float xv = yb[(size_t)ic*HWy];
    #pragma unroll
    for(int j=0;j<8;j++) acc[j] += xv * w[(ocb+j)*CM+ic];
  }
  #pragma unroll
  for(int j=0;j<8;j++) q[((size_t)(b*CM+ocb+j))*HW + p] = acc[j];
}

__global__ void kvconv_kernel(const float* __restrict__ x, const float* __restrict__ kw,
                              const float* __restrict__ vw,
                              float* __restrict__ k, float* __restrict__ v){
  int p = blockIdx.x*256 + threadIdx.x;  // 0..4355 (guard)
  int ocb = blockIdx.y*8; int b = blockIdx.z;
  if(p >= PHW) return;
  int hh = p/66, ww2 = p - hh*66;
  int ih = hh-1, iw = ww2-1;
  bool inb = (ih>=0 && ih<64 && iw>=0 && iw<64);
  float acck[8] = {0,0,0,0,0,0,0,0};
  float accv[8] = {0,0,0,0,0,0,0,0};
  if(inb){
    const float* xb = x + (size_t)b*CM*HW + ih*64 + iw;
    #pragma unroll 4
    for(int ic=0; ic<CM; ic++){
      float xv = xb[(size_t)ic*HW];
      #pragma unroll
      for(int j=0;j<8;j++){ acck[j] += xv*kw[(ocb+j)*CM+ic]; accv[j] += xv*vw[(ocb+j)*CM+ic]; }
    }
  }
  #pragma unroll
  for(int j=0;j<8;j++){
    size_t o = ((size_t)(b*CM+ocb+j))*PHW + p;
    k[o]=acck[j]; v[o]=accv[j];
  }
}

// ---------------- attention ----------------

__global__ void attn_kernel(const float* __restrict__ q, const float* __restrict__ k,
                            const float* __restrict__ v, const float* __restrict__ relh,
                            const float* __restrict__ relw, float* __restrict__ xatt){
  int t = blockIdx.x*256 + threadIdx.x;  // over B*CM*HW
  int p = t & 4095;
  int bc = t >> 12;       // b*128+c
  int c = bc & 127;
  int h = p>>6, w2 = p&63;
  float qv = q[(size_t)bc*HW + p];
  const float* kb = k + (size_t)bc*PHW;
  const float* vb = v + (size_t)bc*PHW;
  float lg[9], vv[9];
  #pragma unroll
  for(int ti=0; ti<3; ti++){
    #pragma unroll
    for(int tj=0; tj<3; tj++){
      int idx = (h+ti)*66 + (w2+tj);
      float rel = (c<64) ? relh[c*3+ti] : relw[(c-64)*3+tj];
      float kv = kb[idx] + rel;
      lg[ti*3+tj] = qv*kv;
      vv[ti*3+tj] = vb[idx];
    }
  }
  float mx = lg[0];
  #pragma unroll
  for(int i=1;i<9;i++) mx = fmaxf(mx, lg[i]);
  float s=0.f, o=0.f;
  #pragma unroll
  for(int i=0;i<9;i++){ float e = __expf(lg[i]-mx); s += e; o += e*vv[i]; }
  xatt[t] = o/s;
}

// ---------------- FFT helpers ----------------

template<int SIGN>
__device__ inline void dft8(const c32* a, c32* X){
  constexpr float C8[8] = {1.f,0.70710678118654752f,0.f,-0.70710678118654752f,
                           -1.f,-0.70710678118654752f,0.f,0.70710678118654752f};
  constexpr float S8[8] = {0.f,0.70710678118654752f,1.f,0.70710678118654752f,
                           0.f,-0.70710678118654752f,-1.f,-0.70710678118654752f};
  #pragma unroll
  for(int kk=0;kk<8;kk++){
    float xr=0.f, xi=0.f;
    #pragma unroll
    for(int n=0;n<8;n++){
      const int j=(n*kk)&7;
      const float wr = C8[j];
      const float wi = SIGN*S8[j];   // e^{SIGN*2pi i j/8}
      xr += a[n].re*wr - a[n].im*wi;
      xi += a[n].re*wi + a[n].im*wr;
    }
    X[kk].re=xr; X[kk].im=xi;
  }
}

// 64-pt FFT along an axis; 32 lines/block x 8 threads; line l: base=(l/l_div)*s1+(l%l_div)*s2
template<int SIGN, bool RIN, bool ROUT>
__global__ void fft64_kernel(const float* in, float* out,
                             int l_div, int s1, int s2, int estride, float scale){
  __shared__ c32 tmp[32][65];
  int ll = threadIdx.x & 31;
  int j  = threadIdx.x >> 5;   // n2 in pass1, k1 in pass2
  int l = blockIdx.x*32 + ll;
  int base = (l/l_div)*s1 + (l%l_div)*s2;
  c32 a[8];
  #pragma unroll
  for(int n1=0;n1<8;n1++){
    int e = n1*8 + j;
    if(RIN){ a[n1].re = in[base + e*estride]; a[n1].im = 0.f; }
    else { const float2* ci = (const float2*)in; float2 t2 = ci[base + e*estride]; a[n1].re=t2.x; a[n1].im=t2.y; }
  }
  c32 A[8];
  dft8<SIGN>(a, A);
  #pragma unroll
  for(int k1=0;k1<8;k1++){
    float ang = SIGN * (TWOPI/64.f) * (float)(j*k1);
    float sn, cs; __sincosf(ang, &sn, &cs);
    c32 t; t.re = A[k1].re*cs - A[k1].im*sn; t.im = A[k1].re*sn + A[k1].im*cs;
    tmp[ll][k1*8+j] = t;
  }
  __syncthreads();
  c32 bv[8];
  #pragma unroll
  for(int n2=0;n2<8;n2++) bv[n2] = tmp[ll][j*8+n2];
  c32 Y[8];
  dft8<SIGN>(bv, Y);
  #pragma unroll
  for(int k2=0;k2<8;k2++){
    int e = j + 8*k2;
    int oi = base + e*estride;
    if(ROUT) out[oi] = Y[k2].re*scale;
    else { float2* co = (float2*)out; co[oi] = make_float2(Y[k2].re*scale, Y[k2].im*scale); }
  }
}

// 128-pt FFT along channel axis, in-place; 16 lines/block x 16 threads
template<int SIGN>
__global__ void fft128_kernel(float* data, float scale){
  __shared__ c32 tmp[16][129];
  int ll = threadIdx.x & 15;
  int j  = threadIdx.x >> 4;   // n2 = 0..15
  int l = blockIdx.x*16 + ll;  // 0..16383 : (b, hf*64+wf)
  int b = l >> 12;
  int rem = l & 4095;
  size_t base = (size_t)b*CM*HW + rem;
  float2* cd = (float2*)data;
  c32 a[8];
  #pragma unroll
  for(int n1=0;n1<8;n1++){
    float2 t2 = cd[base + (size_t)(16*n1 + j)*HW];
    a[n1].re=t2.x; a[n1].im=t2.y;
  }
  c32 A[8];
  dft8<SIGN>(a, A);
  #pragma unroll
  for(int k1=0;k1<8;k1++){
    float ang = SIGN*(TWOPI/128.f)*(float)(j*k1);
    float sn,cs; __sincosf(ang,&sn,&cs);
    c32 t; t.re = A[k1].re*cs - A[k1].im*sn; t.im = A[k1].re*sn + A[k1].im*cs;
    tmp[ll][k1*16 + j] = t;
  }
  __syncthreads();
  int k1 = j & 7, half = j >> 3;
  c32 bv[16];
  #pragma unroll
  for(int n2=0;n2<16;n2++) bv[n2] = tmp[ll][k1*16+n2];
  #pragma unroll
  for(int kk=0;kk<8;kk++){
    int k2 = half*8 + kk;
    float xr=0.f, xi=0.f;
    #pragma unroll
    for(int n2=0;n2<16;n2++){
      float ang = SIGN*(TWOPI/16.f)*(float)((n2*k2)&15);
      float sn,cs; __sincosf(ang,&sn,&cs);
      xr += bv[n2].re*cs - bv[n2].im*sn;
      xi += bv[n2].re*sn + bv[n2].im*cs;
    }
    cd[base + (size_t)(k1 + 8*k2)*HW] = make_float2(xr*scale, xi*scale);
  }
}

// ---------------- channel-mixing einsum (+batch FFT4 + mask) ----------------
// out_ft[kb,o,f] = sum_i Xb[kb,i,f]*w1[i,o,f] ; Xb = FFT4 over batch of Xf
// v4 = v2 (measured-good: 244us, fetch 270MB, write 16MB) + ONE change:
// manual depth-2 software pipeline — prefetch i+1's 6 loads into registers
// while computing i, so each wave hides ~100 cycles of FMA under the next
// load round-trip instead of stalling at vmcnt(0) with zero ILP.
__global__ void einsum_kernel(const float2* __restrict__ Xf, const float* __restrict__ w1r,
                              const float* __restrict__ w1i, float2* __restrict__ OutF){
  // flat launch 2048 blocks; 2048 % 8 == 0 -> this remap is bijective
  int L = blockIdx.x;
  int wk = (L & 7) * 256 + (L >> 3);   // same (wk>>5) f-stripe -> same XCD
  int obase = (wk & 31) * 4;           // 32 o-groups of 4
  int fbase = (wk >> 5) * 64;          // 64 f-stripes of 64
  int fl = threadIdx.x & 63;
  int ol = threadIdx.x >> 6;           // 0..3
  int f = fbase + fl;
  int o = obase + ol;
  c32 acc[4];                          // [kb]
  #pragma unroll
  for(int kb=0;kb<4;kb++){ acc[kb].re=0.f; acc[kb].im=0.f; }
  const float2* X0 = Xf + f;
  const float* wr_base = w1r + (size_t)o*HW + f;
  const float* wi_base = w1i + (size_t)o*HW + f;
  // prologue: load i=0
  float2 cx0 = X0[(size_t)(0*CM)*HW];
  float2 cx1 = X0[(size_t)(1*CM)*HW];
  float2 cx2 = X0[(size_t)(2*CM)*HW];
  float2 cx3 = X0[(size_t)(3*CM)*HW];
  float cwr = wr_base[0];
  float cwi = wi_base[0];
  for(int i=0;i<CM-1;i++){
    // prefetch i+1 (independent of the compute below -> loads fly under FMAs)
    float2 nx0 = X0[(size_t)(0*CM + i+1)*HW];
    float2 nx1 = X0[(size_t)(1*CM + i+1)*HW];
    float2 nx2 = X0[(size_t)(2*CM + i+1)*HW];
    float2 nx3 = X0[(size_t)(3*CM + i+1)*HW];
    float  nwr = wr_base[(size_t)(i+1)*CM*HW];
    float  nwi = wi_base[(size_t)(i+1)*CM*HW];
    // compute i: FFT-4 over batch (sign -1, scale folded into fft128)
    c32 Xb[4];
    Xb[0].re = cx0.x+cx1.x+cx2.x+cx3.x;       Xb[0].im = cx0.y+cx1.y+cx2.y+cx3.y;
    Xb[1].re = cx0.x + cx1.y - cx2.x - cx3.y; Xb[1].im = cx0.y - cx1.x - cx2.y + cx3.x;
    Xb[2].re = cx0.x - cx1.x + cx2.x - cx3.x; Xb[2].im = cx0.y - cx1.y + cx2.y - cx3.y;
    Xb[3].re = cx0.x - cx1.y - cx2.x + cx3.y; Xb[3].im = cx0.y + cx1.x - cx2.y - cx3.x;
    #pragma unroll
    for(int kb=0;kb<4;kb++){
      acc[kb].re += Xb[kb].re*cwr - Xb[kb].im*cwi;
      acc[kb].im += Xb[kb].re*cwi + Xb[kb].im*cwr;
    }
    // rotate
    cx0=nx0; cx1=nx1; cx2=nx2; cx3=nx3; cwr=nwr; cwi=nwi;
  }
  { // epilogue: compute i = CM-1
    c32 Xb[4];
    Xb[0].re = cx0.x+cx1.x+cx2.x+cx3.x;       Xb[0].im = cx0.y+cx1.y+cx2.y+cx3.y;
    Xb[1].re = cx0.x + cx1.y - cx2.x - cx3.y; Xb[1].im = cx0.y - cx1.x - cx2.y + cx3.x;
    Xb[2].re = cx0.x - cx1.x + cx2.x - cx3.x; Xb[2].im = cx0.y - cx1.y + cx2.y - cx3.y;
    Xb[3].re = cx0.x - cx1.y - cx2.x + cx3.y; Xb[3].im = cx0.y + cx1.x - cx2.y - cx3.x;
    #pragma unroll
    for(int kb=0;kb<4;kb++){
      acc[kb].re += Xb[kb].re*cwr - Xb[kb].im*cwi;
      acc[kb].im += Xb[kb].re*cwi + Xb[kb].im*cwr;
    }
  }
  int hf = f>>6, wf = f&63;
  bool masked = (hf<3 || hf>60) && (wf<3 || wf>60);
  #pragma unroll
  for(int kb=0;kb<4;kb++){
    float2 t2 = masked ? make_float2(0.f,0.f) : make_float2(acc[kb].re, acc[kb].im);
    OutF[((size_t)(kb*CM + o))*HW + f] = t2;
  }
}

// ---------------- final combine: w0 conv + blend + bn2 + relu ----------------
__global__ void final_kernel(const float* __restrict__ G, const float* __restrict__ xatt,
                             const float* __restrict__ w0, const float* __restrict__ w0b,
                             const float* __restrict__ r1p, const float* __restrict__ r2p,
                             const float* __restrict__ g2, const float* __restrict__ b2,
                             const float* __restrict__ m2, const float* __restrict__ v2,
                             float* __restrict__ yout){
  int p = blockIdx.x*256 + threadIdx.x;  // 0..4095
  int ocb = blockIdx.y*8; int b = blockIdx.z;
  float r1 = r1p[0], r2 = r2p[0];
  float acc[8] = {0,0,0,0,0,0,0,0};
  const float* xb = xatt + (size_t)b*CM*HW + p;
  #pragma unroll 4
  for(int ic=0; ic<CM; ic++){
    float xv = xb[(size_t)ic*HW];
    #pragma unroll
    for(int j=0;j<8;j++) acc[j] += xv * w0[(ocb+j)*CM + ic];
  }
  #pragma unroll
  for(int j=0;j<8;j++){
    int oc = ocb+j;
    float fam = r1 * G[((size_t)(b*CM+oc))*HW + p] + r2*(acc[j] + w0b[oc]);
    float s = g2[oc]*rsqrtf(v2[oc]+EPSF);
    float bi = b2[oc] - m2[oc]*s;
    float val = fam*s + bi;
    yout[((size_t)(b*CM+oc))*HW + p] = val>0.f?val:0.f;
  }
}

extern "C" void kernel_launch(void* const* d_in, const int* in_sizes, int n_in,
                              void* d_out, int out_size, void* d_ws, size_t ws_size,
                              hipStream_t stream){
  const float* x       = (const float*)d_in[0];
  const float* y       = (const float*)d_in[1];
  const float* conv1_w = (const float*)d_in[2];
  const float* bn1_g   = (const float*)d_in[3];
  const float* bn1_b   = (const float*)d_in[4];
  const float* bn1_m   = (const float*)d_in[5];
  const float* bn1_v   = (const float*)d_in[6];
  const float* q_w     = (const float*)d_in[7];
  const float* k_w     = (const float*)d_in[8];
  const float* v_w     = (const float*)d_in[9];
  const float* rel_h   = (const float*)d_in[10];
  const float* rel_w   = (const float*)d_in[11];
  const float* rate1   = (const float*)d_in[12];
  const float* rate2   = (const float*)d_in[13];
  const float* w1r     = (const float*)d_in[14];
  const float* w1i     = (const float*)d_in[15];
  const float* w0_w    = (const float*)d_in[16];
  const float* w0_b    = (const float*)d_in[17];
  const float* bn2_g   = (const float*)d_in[18];
  const float* bn2_b   = (const float*)d_in[19];
  const float* bn2_m   = (const float*)d_in[20];
  const float* bn2_v   = (const float*)d_in[21];
  (void)in_sizes; (void)n_in; (void)out_size; (void)ws_size;

  char* ws = (char*)d_ws;
  // phase-1 buffers (dead before complex buffers are written)
  float* Y1 = (float*)(ws + 0);                 // 2 MB
  float* Q  = (float*)(ws + 2097152);           // 8 MB
  float* K  = (float*)(ws + 10485760);          // 8.7 MB
  float* V  = (float*)(ws + 19406848);          // 8.7 MB (ends 28,327,936)
  // phase-2 buffers
  float2* E = (float2*)(ws + 0);                // 16 MB  (Xf)
  float2* F = (float2*)(ws + 16777216);         // 16 MB  (out_ft) -> peak ws = 32 MB
  float*  G = (float*)(ws + 0);                 // 8 MB real ifft result (over dead E)

  float* yout = (float*)d_out;
  float* xatt = (float*)d_out + 2097152;

  conv1_kernel<<<dim3(4,16,BB),256,0,stream>>>(y, conv1_w, bn1_g,bn1_b,bn1_m,bn1_v, Y1);
  qconv_kernel<<<dim3(16,16,BB),256,0,stream>>>(Y1, q_w, Q);
  kvconv_kernel<<<dim3(18,16,BB),256,0,stream>>>(x, k_w, v_w, K, V);
  attn_kernel<<<dim3(8192),256,0,stream>>>(Q, K, V, rel_h, rel_w, xatt);

  // forward 2D FFT over (h,w): real xatt -> E, then in-place along h
  fft64_kernel<-1,true,false><<<dim3(1024),256,0,stream>>>(xatt, (float*)E, 64,4096,64, 1, 0.125f);
  fft64_kernel<-1,false,false><<<dim3(1024),256,0,stream>>>((float*)E, (float*)E, 64,4096,1, 64, 0.125f);
  // forward FFT along channel (scale includes 1/sqrt(128) and batch 1/2)
  fft128_kernel<-1><<<dim3(1024),256,0,stream>>>((float*)E, 0.044194173824159216f);
  // batch FFT4 + channel-mix + mask
  einsum_kernel<<<dim3(2048),256,0,stream>>>(E, w1r, w1i, F);
  // inverse 2D FFT over (h,w): in-place along h, then along w -> real G
  fft64_kernel<1,false,false><<<dim3(1024),256,0,stream>>>((float*)F, (float*)F, 64,4096,1, 64, 0.125f);
  fft64_kernel<1,false,true><<<dim3(1024),256,0,stream>>>((float*)F, G, 64,4096,64, 1, 0.125f);

  final_kernel<<<dim3(16,16,BB),256,0,stream>>>(G, xatt, w0_w, w0_b, rate1, rate2,
                                                bn2_g,bn2_b,bn2_m,bn2_v, yout);
}

// Round 5
// 808.473 us; speedup vs baseline: 1.3658x; 1.0211x over previous
//
#include <hip/hip_runtime.h>

#define BB 4
#define CY 256
#define CM 128
#define HW 4096       // 64*64
#define HWy 1024      // 32*32
#define PHW 4356      // 66*66
#define EPSF 1e-5f
#define TWOPI 6.2831853071795864769f

struct c32 { float re, im; };

// ---------------- conv kernels ----------------

__global__ void conv1_kernel(const float* __restrict__ y, const float* __restrict__ w,
                             const float* __restrict__ g, const float* __restrict__ bb,
                             const float* __restrict__ m, const float* __restrict__ v,
                             float* __restrict__ y1){
  int p = blockIdx.x*256 + threadIdx.x;   // 0..1023
  int ocb = blockIdx.y*8;
  int b = blockIdx.z;
  float acc[8] = {0,0,0,0,0,0,0,0};
  const float* yb = y + (size_t)b*CY*HWy + p;
  #pragma unroll 4
  for(int ic=0; ic<CY; ic++){
    float xv = yb[(size_t)ic*HWy];
    #pragma unroll
    for(int j=0;j<8;j++) acc[j] += xv * w[(ocb+j)*CY + ic];
  }
  #pragma unroll
  for(int j=0;j<8;j++){
    int oc = ocb+j;
    float s = g[oc]*rsqrtf(v[oc]+EPSF);
    float bi = bb[oc] - m[oc]*s;
    float r = acc[j]*s + bi;
    y1[((size_t)(b*CM+oc))*HWy + p] = r>0.f?r:0.f;
  }
}

__global__ void qconv_kernel(const float* __restrict__ y1, const float* __restrict__ w,
                             float* __restrict__ q){
  int p = blockIdx.x*256 + threadIdx.x;  // 0..4095
  int ocb = blockIdx.y*8; int b = blockIdx.z;
  int mi = ((p>>7)<<5) + ((p&63)>>1);    // (h/2)*32 + w/2
  float acc[8] = {0,0,0,0,0,0,0,0};
  const float* yb = y1 + (size_t)b*CM*HWy + mi;
  #pragma unroll 4
  for(int ic=0; ic<CM; ic++){
    float xv = yb[(size_t)ic*HWy];
    #pragma unroll
    for(int j=0;j<8;j++) acc[j] += xv * w[(ocb+j)*CM+ic];
  }
  #pragma unroll
  for(int j=0;j<8;j++) q[((size_t)(b*CM+ocb+j))*HW + p] = acc[j];
}

__global__ void kvconv_kernel(const float* __restrict__ x, const float* __restrict__ kw,
                              const float* __restrict__ vw,
                              float* __restrict__ k, float* __restrict__ v){
  int p = blockIdx.x*256 + threadIdx.x;  // 0..4355 (guard)
  int ocb = blockIdx.y*8; int b = blockIdx.z;
  if(p >= PHW) return;
  int hh = p/66, ww2 = p - hh*66;
  int ih = hh-1, iw = ww2-1;
  bool inb = (ih>=0 && ih<64 && iw>=0 && iw<64);
  float acck[8] = {0,0,0,0,0,0,0,0};
  float accv[8] = {0,0,0,0,0,0,0,0};
  if(inb){
    const float* xb = x + (size_t)b*CM*HW + ih*64 + iw;
    #pragma unroll 4
    for(int ic=0; ic<CM; ic++){
      float xv = xb[(size_t)ic*HW];
      #pragma unroll
      for(int j=0;j<8;j++){ acck[j] += xv*kw[(ocb+j)*CM+ic]; accv[j] += xv*vw[(ocb+j)*CM+ic]; }
    }
  }
  #pragma unroll
  for(int j=0;j<8;j++){
    size_t o = ((size_t)(b*CM+ocb+j))*PHW + p;
    k[o]=acck[j]; v[o]=accv[j];
  }
}

// ---------------- attention ----------------

__global__ void attn_kernel(const float* __restrict__ q, const float* __restrict__ k,
                            const float* __restrict__ v, const float* __restrict__ relh,
                            const float* __restrict__ relw, float* __restrict__ xatt){
  int t = blockIdx.x*256 + threadIdx.x;  // over B*CM*HW
  int p = t & 4095;
  int bc = t >> 12;       // b*128+c
  int c = bc & 127;
  int h = p>>6, w2 = p&63;
  float qv = q[(size_t)bc*HW + p];
  const float* kb = k + (size_t)bc*PHW;
  const float* vb = v + (size_t)bc*PHW;
  float lg[9], vv[9];
  #pragma unroll
  for(int ti=0; ti<3; ti++){
    #pragma unroll
    for(int tj=0; tj<3; tj++){
      int idx = (h+ti)*66 + (w2+tj);
      float rel = (c<64) ? relh[c*3+ti] : relw[(c-64)*3+tj];
      float kv = kb[idx] + rel;
      lg[ti*3+tj] = qv*kv;
      vv[ti*3+tj] = vb[idx];
    }
  }
  float mx = lg[0];
  #pragma unroll
  for(int i=1;i<9;i++) mx = fmaxf(mx, lg[i]);
  float s=0.f, o=0.f;
  #pragma unroll
  for(int i=0;i<9;i++){ float e = __expf(lg[i]-mx); s += e; o += e*vv[i]; }
  xatt[t] = o/s;
}

// ---------------- FFT helpers ----------------

template<int SIGN>
__device__ inline void dft8(const c32* a, c32* X){
  constexpr float C8[8] = {1.f,0.70710678118654752f,0.f,-0.70710678118654752f,
                           -1.f,-0.70710678118654752f,0.f,0.70710678118654752f};
  constexpr float S8[8] = {0.f,0.70710678118654752f,1.f,0.70710678118654752f,
                           0.f,-0.70710678118654752f,-1.f,-0.70710678118654752f};
  #pragma unroll
  for(int kk=0;kk<8;kk++){
    float xr=0.f, xi=0.f;
    #pragma unroll
    for(int n=0;n<8;n++){
      const int j=(n*kk)&7;
      const float wr = C8[j];
      const float wi = SIGN*S8[j];   // e^{SIGN*2pi i j/8}
      xr += a[n].re*wr - a[n].im*wi;
      xi += a[n].re*wi + a[n].im*wr;
    }
    X[kk].re=xr; X[kk].im=xi;
  }
}

// 64-pt FFT along an axis; 32 lines/block x 8 threads; line l: base=(l/l_div)*s1+(l%l_div)*s2
template<int SIGN, bool RIN, bool ROUT>
__global__ void fft64_kernel(const float* in, float* out,
                             int l_div, int s1, int s2, int estride, float scale){
  __shared__ c32 tmp[32][65];
  int ll = threadIdx.x & 31;
  int j  = threadIdx.x >> 5;   // n2 in pass1, k1 in pass2
  int l = blockIdx.x*32 + ll;
  int base = (l/l_div)*s1 + (l%l_div)*s2;
  c32 a[8];
  #pragma unroll
  for(int n1=0;n1<8;n1++){
    int e = n1*8 + j;
    if(RIN){ a[n1].re = in[base + e*estride]; a[n1].im = 0.f; }
    else { const float2* ci = (const float2*)in; float2 t2 = ci[base + e*estride]; a[n1].re=t2.x; a[n1].im=t2.y; }
  }
  c32 A[8];
  dft8<SIGN>(a, A);
  #pragma unroll
  for(int k1=0;k1<8;k1++){
    float ang = SIGN * (TWOPI/64.f) * (float)(j*k1);
    float sn, cs; __sincosf(ang, &sn, &cs);
    c32 t; t.re = A[k1].re*cs - A[k1].im*sn; t.im = A[k1].re*sn + A[k1].im*cs;
    tmp[ll][k1*8+j] = t;
  }
  __syncthreads();
  c32 bv[8];
  #pragma unroll
  for(int n2=0;n2<8;n2++) bv[n2] = tmp[ll][j*8+n2];
  c32 Y[8];
  dft8<SIGN>(bv, Y);
  #pragma unroll
  for(int k2=0;k2<8;k2++){
    int e = j + 8*k2;
    int oi = base + e*estride;
    if(ROUT) out[oi] = Y[k2].re*scale;
    else { float2* co = (float2*)out; co[oi] = make_float2(Y[k2].re*scale, Y[k2].im*scale); }
  }
}

// 128-pt FFT along channel axis, in-place; 16 lines/block x 16 threads
template<int SIGN>
__global__ void fft128_kernel(float* data, float scale){
  __shared__ c32 tmp[16][129];
  int ll = threadIdx.x & 15;
  int j  = threadIdx.x >> 4;   // n2 = 0..15
  int l = blockIdx.x*16 + ll;  // 0..16383 : (b, hf*64+wf)
  int b = l >> 12;
  int rem = l & 4095;
  size_t base = (size_t)b*CM*HW + rem;
  float2* cd = (float2*)data;
  c32 a[8];
  #pragma unroll
  for(int n1=0;n1<8;n1++){
    float2 t2 = cd[base + (size_t)(16*n1 + j)*HW];
    a[n1].re=t2.x; a[n1].im=t2.y;
  }
  c32 A[8];
  dft8<SIGN>(a, A);
  #pragma unroll
  for(int k1=0;k1<8;k1++){
    float ang = SIGN*(TWOPI/128.f)*(float)(j*k1);
    float sn,cs; __sincosf(ang,&sn,&cs);
    c32 t; t.re = A[k1].re*cs - A[k1].im*sn; t.im = A[k1].re*sn + A[k1].im*cs;
    tmp[ll][k1*16 + j] = t;
  }
  __syncthreads();
  int k1 = j & 7, half = j >> 3;
  c32 bv[16];
  #pragma unroll
  for(int n2=0;n2<16;n2++) bv[n2] = tmp[ll][k1*16+n2];
  #pragma unroll
  for(int kk=0;kk<8;kk++){
    int k2 = half*8 + kk;
    float xr=0.f, xi=0.f;
    #pragma unroll
    for(int n2=0;n2<16;n2++){
      float ang = SIGN*(TWOPI/16.f)*(float)((n2*k2)&15);
      float sn,cs; __sincosf(ang,&sn,&cs);
      xr += bv[n2].re*cs - bv[n2].im*sn;
      xi += bv[n2].re*sn + bv[n2].im*cs;
    }
    cd[base + (size_t)(k1 + 8*k2)*HW] = make_float2(xr*scale, xi*scale);
  }
}

// ---------------- channel-mixing einsum (+batch FFT4 + mask) ----------------
// out_ft[kb,o,f] = sum_i Xb[kb,i,f]*w1[i,o,f] ; Xb = FFT4 over batch of Xf
// v5: DRAM-granularity restructure. Old: one wave = one o, 64 f -> every w
// load was a 256B request at 2MB stride (row-activate-bound HBM, ~20% eff,
// all prior versions stuck at 1.2-1.7 TB/s). New: block = one o x 512-f
// chunk -> each i-step reads w1r/w1i as 2KB CONTIGUOUS per array. fc = bid&7
// pins each f-chunk to one XCD (round-robin dispatch heuristic): the chunk's
// Xf slice (4kb x 128i x 512f = 2MB) stays L2-resident per XCD; w streams.
__global__ void einsum_kernel(const float2* __restrict__ Xf, const float* __restrict__ w1r,
                              const float* __restrict__ w1i, float2* __restrict__ OutF){
  int bid = blockIdx.x;          // 0..1023
  int fc  = bid & 7;             // f-chunk (and XCD) id
  int o   = bid >> 3;            // 0..127 output channel
  int fho = fc*256 + threadIdx.x;        // float4-pair index: f0 = 2*fho
  int f0  = fho*2;
  const float4* X4  = (const float4*)Xf; // float4 = 2 consecutive f (re,im,re,im)
  const float2* wr2 = (const float2*)w1r;
  const float2* wi2 = (const float2*)w1i;
  float accr[4][2] = {{0,0},{0,0},{0,0},{0,0}};
  float acci[4][2] = {{0,0},{0,0},{0,0},{0,0}};
  for(int i=0;i<CM;i++){
    float4 x0 = X4[(size_t)(0*CM+i)*2048 + fho];
    float4 x1 = X4[(size_t)(1*CM+i)*2048 + fho];
    float4 x2 = X4[(size_t)(2*CM+i)*2048 + fho];
    float4 x3 = X4[(size_t)(3*CM+i)*2048 + fho];
    float2 wr = wr2[(size_t)(i*CM+o)*2048 + fho];
    float2 wi = wi2[(size_t)(i*CM+o)*2048 + fho];
    // FFT-4 over batch (sign -1; scale folded into fft128), f-sub 0 (.x,.y)
    {
      float br0 = x0.x+x1.x+x2.x+x3.x,  bi0 = x0.y+x1.y+x2.y+x3.y;
      float br1 = x0.x+x1.y-x2.x-x3.y,  bi1 = x0.y-x1.x-x2.y+x3.x;
      float br2 = x0.x-x1.x+x2.x-x3.x,  bi2 = x0.y-x1.y+x2.y-x3.y;
      float br3 = x0.x-x1.y-x2.x+x3.y,  bi3 = x0.y+x1.x-x2.y-x3.x;
      accr[0][0] += br0*wr.x - bi0*wi.x;  acci[0][0] += br0*wi.x + bi0*wr.x;
      accr[1][0] += br1*wr.x - bi1*wi.x;  acci[1][0] += br1*wi.x + bi1*wr.x;
      accr[2][0] += br2*wr.x - bi2*wi.x;  acci[2][0] += br2*wi.x + bi2*wr.x;
      accr[3][0] += br3*wr.x - bi3*wi.x;  acci[3][0] += br3*wi.x + bi3*wr.x;
    }
    // f-sub 1 (.z,.w)
    {
      float br0 = x0.z+x1.z+x2.z+x3.z,  bi0 = x0.w+x1.w+x2.w+x3.w;
      float br1 = x0.z+x1.w-x2.z-x3.w,  bi1 = x0.w-x1.z-x2.w+x3.z;
      float br2 = x0.z-x1.z+x2.z-x3.z,  bi2 = x0.w-x1.w+x2.w-x3.w;
      float br3 = x0.z-x1.w-x2.z+x3.w,  bi3 = x0.w+x1.z-x2.w-x3.z;
      accr[0][1] += br0*wr.y - bi0*wi.y;  acci[0][1] += br0*wi.y + bi0*wr.y;
      accr[1][1] += br1*wr.y - bi1*wi.y;  acci[1][1] += br1*wi.y + bi1*wr.y;
      accr[2][1] += br2*wr.y - bi2*wi.y;  acci[2][1] += br2*wi.y + bi2*wr.y;
      accr[3][1] += br3*wr.y - bi3*wi.y;  acci[3][1] += br3*wi.y + bi3*wr.y;
    }
  }
  int hf = f0>>6;
  int wf0 = f0&63, wf1 = wf0+1;    // f0 even -> no hf crossing
  bool mh = (hf<3 || hf>60);
  bool m0 = mh && (wf0<3 || wf0>60);
  bool m1 = mh && (wf1<3 || wf1>60);
  float4* O4 = (float4*)OutF;
  #pragma unroll
  for(int kb=0;kb<4;kb++){
    float4 t2;
    t2.x = m0 ? 0.f : accr[kb][0];
    t2.y = m0 ? 0.f : acci[kb][0];
    t2.z = m1 ? 0.f : accr[kb][1];
    t2.w = m1 ? 0.f : acci[kb][1];
    O4[(size_t)(kb*CM+o)*2048 + fho] = t2;
  }
}

// ---------------- final combine: w0 conv + blend + bn2 + relu ----------------
__global__ void final_kernel(const float* __restrict__ G, const float* __restrict__ xatt,
                             const float* __restrict__ w0, const float* __restrict__ w0b,
                             const float* __restrict__ r1p, const float* __restrict__ r2p,
                             const float* __restrict__ g2, const float* __restrict__ b2,
                             const float* __restrict__ m2, const float* __restrict__ v2,
                             float* __restrict__ yout){
  int p = blockIdx.x*256 + threadIdx.x;  // 0..4095
  int ocb = blockIdx.y*8; int b = blockIdx.z;
  float r1 = r1p[0], r2 = r2p[0];
  float acc[8] = {0,0,0,0,0,0,0,0};
  const float* xb = xatt + (size_t)b*CM*HW + p;
  #pragma unroll 4
  for(int ic=0; ic<CM; ic++){
    float xv = xb[(size_t)ic*HW];
    #pragma unroll
    for(int j=0;j<8;j++) acc[j] += xv * w0[(ocb+j)*CM + ic];
  }
  #pragma unroll
  for(int j=0;j<8;j++){
    int oc = ocb+j;
    float fam = r1 * G[((size_t)(b*CM+oc))*HW + p] + r2*(acc[j] + w0b[oc]);
    float s = g2[oc]*rsqrtf(v2[oc]+EPSF);
    float bi = b2[oc] - m2[oc]*s;
    float val = fam*s + bi;
    yout[((size_t)(b*CM+oc))*HW + p] = val>0.f?val:0.f;
  }
}

extern "C" void kernel_launch(void* const* d_in, const int* in_sizes, int n_in,
                              void* d_out, int out_size, void* d_ws, size_t ws_size,
                              hipStream_t stream){
  const float* x       = (const float*)d_in[0];
  const float* y       = (const float*)d_in[1];
  const float* conv1_w = (const float*)d_in[2];
  const float* bn1_g   = (const float*)d_in[3];
  const float* bn1_b   = (const float*)d_in[4];
  const float* bn1_m   = (const float*)d_in[5];
  const float* bn1_v   = (const float*)d_in[6];
  const float* q_w     = (const float*)d_in[7];
  const float* k_w     = (const float*)d_in[8];
  const float* v_w     = (const float*)d_in[9];
  const float* rel_h   = (const float*)d_in[10];
  const float* rel_w   = (const float*)d_in[11];
  const float* rate1   = (const float*)d_in[12];
  const float* rate2   = (const float*)d_in[13];
  const float* w1r     = (const float*)d_in[14];
  const float* w1i     = (const float*)d_in[15];
  const float* w0_w    = (const float*)d_in[16];
  const float* w0_b    = (const float*)d_in[17];
  const float* bn2_g   = (const float*)d_in[18];
  const float* bn2_b   = (const float*)d_in[19];
  const float* bn2_m   = (const float*)d_in[20];
  const float* bn2_v   = (const float*)d_in[21];
  (void)in_sizes; (void)n_in; (void)out_size; (void)ws_size;

  char* ws = (char*)d_ws;
  // phase-1 buffers (dead before complex buffers are written)
  float* Y1 = (float*)(ws + 0);                 // 2 MB
  float* Q  = (float*)(ws + 2097152);           // 8 MB
  float* K  = (float*)(ws + 10485760);          // 8.7 MB
  float* V  = (float*)(ws + 19406848);          // 8.7 MB (ends 28,327,936)
  // phase-2 buffers
  float2* E = (float2*)(ws + 0);                // 16 MB  (Xf)
  float2* F = (float2*)(ws + 16777216);         // 16 MB  (out_ft) -> peak ws = 32 MB
  float*  G = (float*)(ws + 0);                 // 8 MB real ifft result (over dead E)

  float* yout = (float*)d_out;
  float* xatt = (float*)d_out + 2097152;

  conv1_kernel<<<dim3(4,16,BB),256,0,stream>>>(y, conv1_w, bn1_g,bn1_b,bn1_m,bn1_v, Y1);
  qconv_kernel<<<dim3(16,16,BB),256,0,stream>>>(Y1, q_w, Q);
  kvconv_kernel<<<dim3(18,16,BB),256,0,stream>>>(x, k_w, v_w, K, V);
  attn_kernel<<<dim3(8192),256,0,stream>>>(Q, K, V, rel_h, rel_w, xatt);

  // forward 2D FFT over (h,w): real xatt -> E, then in-place along h
  fft64_kernel<-1,true,false><<<dim3(1024),256,0,stream>>>(xatt, (float*)E, 64,4096,64, 1, 0.125f);
  fft64_kernel<-1,false,false><<<dim3(1024),256,0,stream>>>((float*)E, (float*)E, 64,4096,1, 64, 0.125f);
  // forward FFT along channel (scale includes 1/sqrt(128) and batch 1/2)
  fft128_kernel<-1><<<dim3(1024),256,0,stream>>>((float*)E, 0.044194173824159216f);
  // batch FFT4 + channel-mix + mask (contiguous-w restructure)
  einsum_kernel<<<dim3(1024),256,0,stream>>>(E, w1r, w1i, F);
  // inverse 2D FFT over (h,w): in-place along h, then along w -> real G
  fft64_kernel<1,false,false><<<dim3(1024),256,0,stream>>>((float*)F, (float*)F, 64,4096,1, 64, 0.125f);
  fft64_kernel<1,false,true><<<dim3(1024),256,0,stream>>>((float*)F, G, 64,4096,64, 1, 0.125f);

  final_kernel<<<dim3(16,16,BB),256,0,stream>>>(G, xatt, w0_w, w0_b, rate1, rate2,
                                                bn2_g,bn2_b,bn2_m,bn2_v, yout);
}